// Round 10
// baseline (733.272 us; speedup 1.0000x reference)
//
#include <hip/hip_runtime.h>
#include <hip/hip_bf16.h>
#include <hip/hip_fp16.h>
#include <cmath>

#define BB   8
#define CIN  8
#define TT   12
#define HH   128
#define WW   128
#define HID  32
#define CCOMB 40
#define HW   (HH * WW)
#define NBLK 512

// LDS (u16): tile1 [20x20 px][40] @0 (x ch0..7, h ch8..39);
// tile2 (rh, co 0..31) [18x18][36] @16000 ; tileU fp16 [256][36] @27664
// total 36880 u16 = 73,760 B -> 2 blocks/CU
#define S1    40
#define T1W   20
#define OFF2  16000
#define S2    36
#define OFFU  27664
#define SMEM_U16 36880

typedef __attribute__((ext_vector_type(8))) short sv8;
typedef __attribute__((ext_vector_type(4))) short sv4;
typedef __attribute__((ext_vector_type(4))) float f32x4;
typedef unsigned short u16;
typedef unsigned long long ull;

__device__ inline u16 f2bf(float f) {
    union { float f; unsigned u; } v; v.f = f;
    unsigned u = v.u;
    return (u16)((u + 0x7FFFu + ((u >> 16) & 1u)) >> 16);
}
__device__ inline float bf2f(u16 h) {
    union { unsigned u; float f; } v; v.u = ((unsigned)h) << 16; return v.f;
}
__device__ inline float sigmoid_fast(float x) { return 1.f / (1.f + __expf(-x)); }
__device__ inline float tanh_fast(float z) {
    float a = fabsf(z);
    float r = 1.f - 2.f / (__expf(2.f * a) + 1.f);
    return copysignf(r, z);
}

// 2-px outer ring of the 20x20 tile (144 px): i -> (r,c)
__device__ __forceinline__ void band_rc(int i, int& r, int& c) {
    if (i < 40)      { r = i / 20;            c = i % 20; }            // rows 0,1
    else if (i < 80) { int j = i - 40; r = 18 + j / 20; c = j % 20; }  // rows 18,19
    else             { int j = i - 80; r = 2 + (j >> 2);
                       int k = j & 3;  c = (k < 2) ? k : 16 + k; }     // cols 0,1,18,19
}

// ---------------------------------------------------------------------------
// weight pack: [Gall(6)][f=kx*4+ks (12)][lane(64)][8 bf16]
// ---------------------------------------------------------------------------
__device__ inline sv8 gather_wfrag(const float* __restrict__ W,
                                   int co, int g, int kx, int ks) {
    int k0 = ks * 32 + g * 8;
    sv8 f;
    if (k0 < 120) {
        int ky  = k0 / 40;
        int ci0 = k0 - ky * 40;
#pragma unroll
        for (int i = 0; i < 8; ++i)
            f[i] = (short)f2bf(W[(((size_t)co * CCOMB + ci0 + i) * 3 + ky) * 3 + kx]);
    } else {
#pragma unroll
        for (int i = 0; i < 8; ++i) f[i] = 0;
    }
    return f;
}

__global__ void pack_weights(const float* __restrict__ Wg,
                             const float* __restrict__ Wc,
                             u16* __restrict__ pack) {
    int tid = blockIdx.x * blockDim.x + threadIdx.x;
    if (tid >= 6 * 12 * 64) return;
    int lane = tid & 63;
    int f    = (tid >> 6) % 12;
    int Gall = tid / (12 * 64);
    int kx = f >> 2, ks = f & 3;
    int g = lane >> 4;
    sv8 v;
    if (Gall < 4) v = gather_wfrag(Wg, Gall * 16 + (lane & 15), g, kx, ks);
    else          v = gather_wfrag(Wc, (Gall - 4) * 16 + (lane & 15), g, kx, ks);
    *(sv8*)&pack[(size_t)tid * 8] = v;
}

__global__ __launch_bounds__(256) void x_to_bf16(const float* __restrict__ x,
                                                 u16* __restrict__ xbf) {
    int gid = blockIdx.x * 256 + threadIdx.x;
    if (gid >= BB * TT * HW) return;
    int p  = gid & (HW - 1);
    int bt = gid >> 14;
    int t = bt % TT, b = bt / TT;
    sv8 v;
#pragma unroll
    for (int c = 0; c < 8; ++c)
        v[c] = (short)f2bf(x[(((size_t)b * CIN + c) * TT + t) * HW + p]);
    *(sv8*)&xbf[(size_t)gid * 8] = v;
}

// ---------------------------------------------------------------------------
// Persistent GRU: 512 blocks x 512 threads (8 waves), 2 blocks/CU =
// 16 waves/CU. Weights reloaded per phase from L2 (out uses nt stores so
// the pack stays L2-hot). Fence-free p2p sync, flag posted before out-writes.
// ---------------------------------------------------------------------------
__global__ __launch_bounds__(512, 4) void gru_persist(
    const u16* __restrict__ xbf, const u16* __restrict__ wpack,
    const float* __restrict__ bg, const float* __restrict__ bc,
    u16* __restrict__ hG, int* __restrict__ flags,
    float* __restrict__ out, float* __restrict__ hlast)
{
    __shared__ __align__(16) u16 smem[SMEM_U16];
    const int id = blockIdx.x;
    const int b = id & 7, tau = id >> 3;
    const int bx = tau & 7, by = tau >> 3;
    const int x0 = bx * 16, y0 = by * 16;
    const int tid = threadIdx.x, lane = tid & 63, w = tid >> 6;
    const int m = lane & 15, g = lane >> 4;

    // neighbor ids (8 dirs), -1 if outside image (8x8 tile grid)
    int nbr = -1;
    if (tid < 8) {
        const int dxs[8] = {-1, 0, 1, -1, 1, -1, 0, 1};
        const int dys[8] = {-1, -1, -1, 0, 0, 1, 1, 1};
        int nx = bx + dxs[tid], ny = by + dys[tid];
        if ((unsigned)nx < 8u && (unsigned)ny < 8u)
            nbr = ((ny * 8 + nx) * 8 + b);
    }

    int kyv[4], ci0v[4];
#pragma unroll
    for (int ks = 0; ks < 4; ++ks) {
        int k0 = ks * 32 + g * 8;
        kyv[ks] = 0; ci0v[ks] = 0;
        if (k0 < 120) { kyv[ks] = k0 / 40; ci0v[ks] = k0 - kyv[ks] * 40; }
    }

    const int gw = w & 3;          // gates co-group
    const int ph = w >> 2;         // gates n-tile parity
    const int cg = w & 1;          // cand co-group
    const int rp = w >> 1;         // cand row-quarter (0..3)

    const int co0g = gw * 16 + g * 4;
    const int co0c = cg * 16 + g * 4;
    float biasg[4], biasc[4];
#pragma unroll
    for (int r = 0; r < 4; ++r) { biasg[r] = bg[co0g + r]; biasc[r] = bc[co0c + r]; }

    // zero tile1 h slots (h0 = 0), 400 px x 4 q
    for (int i = tid; i < 1600; i += 512) {
        int px = i >> 2, q = i & 3;
        sv8 z = {};
        *(sv8*)&smem[px * S1 + 8 + q * 8] = z;
    }

    const u16* xbB = xbf + (size_t)b * TT * HW * 8;
    const size_t planeElems = (size_t)BB * HW * 32;

    for (int t = 0; t < TT; ++t) {
        const u16* hGr = hG + (size_t)(t & 1) * planeElems + (size_t)b * HW * 32;
        u16*       hGw = hG + (size_t)((t + 1) & 1) * planeElems + (size_t)b * HW * 32;

        // ---- gates weights: issue early, in flight during wait ----
        sv8 wf[12];
#pragma unroll
        for (int f = 0; f < 12; ++f)
            wf[f] = *(const sv8*)&wpack[(((size_t)gw * 12 + f) * 64 + lane) * 8];

        // ---- stage x (400 px) — independent of neighbor progress ----
        const u16* xb = xbB + (size_t)t * HW * 8;
        if (tid < 400) {
            int r = tid / 20, c = tid - r * 20;
            int gy = y0 + r - 2, gx = x0 + c - 2;
            sv8 v = {};
            if ((unsigned)gy < 128u && (unsigned)gx < 128u)
                v = *(const sv8*)&xb[(size_t)(gy * WW + gx) * 8];
            *(sv8*)&smem[tid * S1] = v;
        }

        // ---- wait for neighbors to finish step t-1 ----
        if (t > 0) {
            if (tid < 8 && nbr >= 0) {
                while (__hip_atomic_load(&flags[nbr * 32], __ATOMIC_RELAXED,
                                         __HIP_MEMORY_SCOPE_AGENT) < t)
                    __builtin_amdgcn_s_sleep(8);
            }
            __syncthreads();
        }

        // ---- stage h ring (144 px x 32ch) via 8B relaxed atomics ----
        for (int idx = tid; idx < 144 * 8; idx += 512) {
            int i = idx >> 3, q = idx & 7;
            int r, c; band_rc(i, r, c);
            int gy = y0 + r - 2, gx = x0 + c - 2;
            ull v = 0;
            if ((unsigned)gy < 128u && (unsigned)gx < 128u)
                v = __hip_atomic_load((const ull*)&hGr[(size_t)(gy * WW + gx) * 32 + q * 4],
                                      __ATOMIC_RELAXED, __HIP_MEMORY_SCOPE_AGENT);
            *(ull*)&smem[(r * T1W + c) * S1 + 8 + q * 4] = v;
        }
        __syncthreads();

        // ---- gates conv over 18x18 region: 21 n-tiles, parity-split ----
        for (int bt3 = 0; bt3 < 3; ++bt3) {
            int yyv[4], xxv[4]; bool val[4];
#pragma unroll
            for (int jj = 0; jj < 4; ++jj) {
                int k = bt3 * 4 + jj;
                int p = (2 * k + ph) * 16 + m;
                val[jj] = (k < 11 - ph) && (p < 324);
                int px = val[jj] ? p : 323;
                yyv[jj] = px / 18; xxv[jj] = px - yyv[jj] * 18;
            }
            f32x4 acc[4];
#pragma unroll
            for (int jj = 0; jj < 4; ++jj) acc[jj] = (f32x4){0.f, 0.f, 0.f, 0.f};
#pragma unroll
            for (int kx = 0; kx < 3; ++kx)
#pragma unroll
                for (int ks = 0; ks < 4; ++ks) {
#pragma unroll
                    for (int jj = 0; jj < 4; ++jj) {
                        sv8 bv = *(const sv8*)&smem[((yyv[jj] + kyv[ks]) * T1W + xxv[jj] + kx) * S1 + ci0v[ks]];
                        acc[jj] = __builtin_amdgcn_mfma_f32_16x16x32_bf16(wf[kx * 4 + ks], bv, acc[jj], 0, 0, 0);
                    }
                }
            // epilogue A
            if (gw < 2) {      // reset -> rh into tile2 (LDS only)
#pragma unroll
                for (int jj = 0; jj < 4; ++jj) {
                    int yy = yyv[jj], xx = xxv[jj];
                    sv4 h4 = *(const sv4*)&smem[((yy + 1) * T1W + xx + 1) * S1 + 8 + co0g];
                    sv4 rh4;
#pragma unroll
                    for (int r = 0; r < 4; ++r) {
                        float gv = sigmoid_fast(acc[jj][r] + biasg[r]);
                        rh4[r] = (short)f2bf(gv * bf2f((u16)h4[r]));
                    }
                    if (val[jj])
                        *(sv4*)&smem[OFF2 + (yy * 18 + xx) * S2 + co0g] = rh4;
                }
            } else {           // update -> tileU (interior 16x16 only)
                int u0 = co0g - 32;
#pragma unroll
                for (int jj = 0; jj < 4; ++jj) {
                    int yy = yyv[jj], xx = xxv[jj];
                    sv4 uv;
#pragma unroll
                    for (int r = 0; r < 4; ++r)
                        uv[r] = (short)__half_as_ushort(__float2half(sigmoid_fast(acc[jj][r] + biasg[r])));
                    if (val[jj] && yy >= 1 && yy <= 16 && xx >= 1 && xx <= 16)
                        *(sv4*)&smem[OFFU + ((yy - 1) * 16 + (xx - 1)) * S2 + u0] = uv;
                }
            }
        }

        // ---- cand weights: issue before barrier, in flight across it ----
        sv8 wc[12];
#pragma unroll
        for (int f = 0; f < 12; ++f)
            wc[f] = *(const sv8*)&wpack[(((size_t)(4 + cg) * 12 + f) * 64 + lane) * 8];

        __syncthreads();

        // ---- cand conv over 4 rows (rp quarter) + blend ----
        f32x4 a2[4];
#pragma unroll
        for (int jr = 0; jr < 4; ++jr) a2[jr] = (f32x4){0.f, 0.f, 0.f, 0.f};
#pragma unroll
        for (int kx = 0; kx < 3; ++kx)
#pragma unroll
            for (int ks = 0; ks < 4; ++ks) {
#pragma unroll
                for (int jr = 0; jr < 4; ++jr) {
                    int j = rp * 4 + jr;
                    int a_x  = ((j + 1 + kyv[ks]) * T1W + m + 1 + kx) * S1;
                    int a_rh = OFF2 + ((j + kyv[ks]) * 18 + m + kx) * S2 + (ci0v[ks] - 8);
                    int addr = (ci0v[ks] == 0) ? a_x : a_rh;
                    sv4 lo = *(const sv4*)&smem[addr];
                    sv4 hi = *(const sv4*)&smem[addr + 4];
                    sv8 bv = __builtin_shufflevector(lo, hi, 0, 1, 2, 3, 4, 5, 6, 7);
                    a2[jr] = __builtin_amdgcn_mfma_f32_16x16x32_bf16(wc[kx * 4 + ks], bv, a2[jr], 0, 0, 0);
                }
            }

        // blend; keep h_next in a2; ring stores now, out stores after flag
#pragma unroll
        for (int jr = 0; jr < 4; ++jr) {
            int j = rp * 4 + jr;
            int gy = y0 + j, gx = x0 + m;
            int ctr = ((j + 2) * T1W + m + 2) * S1;
            sv4 h4 = *(const sv4*)&smem[ctr + 8 + co0c];
            int ub = OFFU + (j * 16 + m) * S2 + co0c;
            sv4 hn4;
#pragma unroll
            for (int r = 0; r < 4; ++r) {
                float cv   = tanh_fast(a2[jr][r] + biasc[r]);
                float uu   = __half2float(__ushort_as_half((u16)smem[ub + r]));
                float hold = bf2f((u16)h4[r]);
                float hn = (1.f - uu) * hold + uu * cv;
                a2[jr][r] = hn;
                hn4[r] = (short)f2bf(hn);
            }
            *(sv4*)&smem[ctr + 8 + co0c] = hn4;   // persist h in LDS
            if (j <= 1 || j >= 14 || m <= 1 || m >= 14) {
                union { sv4 s; ull u; } cvt; cvt.s = hn4;
                __hip_atomic_store((ull*)&hGw[(size_t)(gy * WW + gx) * 32 + co0c],
                                   cvt.u, __ATOMIC_RELAXED, __HIP_MEMORY_SCOPE_AGENT);
            }
        }

        // ring stores at coherence point -> post flag (out stores NOT yet issued)
        asm volatile("s_waitcnt vmcnt(0)" ::: "memory");
        __syncthreads();
        if (tid == 0)
            __hip_atomic_store(&flags[id * 32], t + 1, __ATOMIC_RELAXED,
                               __HIP_MEMORY_SCOPE_AGENT);

        // ---- out (+hlast) stores, non-temporal: drain during next wait ----
#pragma unroll
        for (int jr = 0; jr < 4; ++jr) {
            int j = rp * 4 + jr;
            int gy = y0 + j, gx = x0 + m;
#pragma unroll
            for (int r = 0; r < 4; ++r) {
                __builtin_nontemporal_store(a2[jr][r],
                    &out[(((size_t)b * HID + co0c + r) * TT + t) * HW + (size_t)gy * WW + gx]);
                if (t == TT - 1)
                    __builtin_nontemporal_store(a2[jr][r],
                        &hlast[((size_t)b * HID + co0c + r) * HW + (size_t)gy * WW + gx]);
            }
        }
    }
}

extern "C" void kernel_launch(void* const* d_in, const int* in_sizes, int n_in,
                              void* d_out, int out_size, void* d_ws, size_t ws_size,
                              hipStream_t stream) {
    const float* x  = (const float*)d_in[0];
    const float* Wg = (const float*)d_in[1];
    const float* bg = (const float*)d_in[2];
    const float* Wc = (const float*)d_in[3];
    const float* bc = (const float*)d_in[4];

    float* out   = (float*)d_out;
    float* hlast = out + (size_t)BB * HID * TT * HW;

    const size_t PLANEB = (size_t)BB * HW * 32 * sizeof(u16);    // 8.39 MB
    const size_t PACKB  = (size_t)6 * 12 * 64 * 8 * sizeof(u16); // 73.7 KB
    const size_t FLAGB  = (size_t)NBLK * 32 * sizeof(int);       // 64 KB
    char* ws = (char*)d_ws;
    u16* hG    = (u16*)ws;                        // 2 planes
    u16* wpack = (u16*)(ws + 2 * PLANEB);
    int* flags = (int*)(ws + 2 * PLANEB + PACKB);
    u16* xbf   = (u16*)(ws + 2 * PLANEB + PACKB + FLAGB);

    pack_weights<<<(6 * 12 * 64 + 255) / 256, 256, 0, stream>>>(Wg, Wc, wpack);
    x_to_bf16<<<(BB * TT * HW) / 256, 256, 0, stream>>>(x, xbf);
    hipMemsetAsync(hG, 0, PLANEB, stream);        // plane 0 = h0 = 0
    hipMemsetAsync(flags, 0, FLAGB, stream);

    gru_persist<<<NBLK, 512, 0, stream>>>(xbf, wpack, bg, bc, hG, flags,
                                          out, hlast);
}

// Round 11
// 464.237 us; speedup vs baseline: 1.5795x; 1.5795x over previous
//
#include <hip/hip_runtime.h>
#include <hip/hip_bf16.h>
#include <hip/hip_fp16.h>
#include <cmath>

#define BB   8
#define CIN  8
#define TT   12
#define HH   128
#define WW   128
#define HID  32
#define CCOMB 40
#define HW   (HH * WW)
#define NBLK 512

// LDS (u16): tile1 [20x20 px][44] @0 (x ch0..7, h ch8..39, pad 40..43);
// tile2 (rh, co 0..31) [18x18][36] @17600 ; tileU fp16 [256][36] @29264
// total 38,480 u16 = 76,960 B -> 2 blocks/CU. Stride 44 (88 B = 22 banks)
// gives <=2-way LDS conflicts (free) vs 8-way at stride 40.
#define S1    44
#define T1W   20
#define OFF2  17600
#define S2    36
#define OFFU  29264
#define SMEM_U16 38480

typedef __attribute__((ext_vector_type(8))) short sv8;
typedef __attribute__((ext_vector_type(4))) short sv4;
typedef __attribute__((ext_vector_type(4))) float f32x4;
typedef unsigned short u16;
typedef unsigned long long ull;

__device__ inline u16 f2bf(float f) {
    union { float f; unsigned u; } v; v.f = f;
    unsigned u = v.u;
    return (u16)((u + 0x7FFFu + ((u >> 16) & 1u)) >> 16);
}
__device__ inline float bf2f(u16 h) {
    union { unsigned u; float f; } v; v.u = ((unsigned)h) << 16; return v.f;
}
__device__ inline float sigmoid_fast(float x) { return 1.f / (1.f + __expf(-x)); }
__device__ inline float tanh_fast(float z) {
    float a = fabsf(z);
    float r = 1.f - 2.f / (__expf(2.f * a) + 1.f);
    return copysignf(r, z);
}

// 2-px outer ring of the 20x20 tile (144 px): i -> (r,c)
__device__ __forceinline__ void band_rc(int i, int& r, int& c) {
    if (i < 40)      { r = i / 20;            c = i % 20; }            // rows 0,1
    else if (i < 80) { int j = i - 40; r = 18 + j / 20; c = j % 20; }  // rows 18,19
    else             { int j = i - 80; r = 2 + (j >> 2);
                       int k = j & 3;  c = (k < 2) ? k : 16 + k; }     // cols 0,1,18,19
}

// ---------------------------------------------------------------------------
// weight pack: [Gall(6)][f=kx*4+ks (12)][lane(64)][8 bf16]
// ---------------------------------------------------------------------------
__device__ inline sv8 gather_wfrag(const float* __restrict__ W,
                                   int co, int g, int kx, int ks) {
    int k0 = ks * 32 + g * 8;
    sv8 f;
    if (k0 < 120) {
        int ky  = k0 / 40;
        int ci0 = k0 - ky * 40;
#pragma unroll
        for (int i = 0; i < 8; ++i)
            f[i] = (short)f2bf(W[(((size_t)co * CCOMB + ci0 + i) * 3 + ky) * 3 + kx]);
    } else {
#pragma unroll
        for (int i = 0; i < 8; ++i) f[i] = 0;
    }
    return f;
}

__global__ void pack_weights(const float* __restrict__ Wg,
                             const float* __restrict__ Wc,
                             u16* __restrict__ pack) {
    int tid = blockIdx.x * blockDim.x + threadIdx.x;
    if (tid >= 6 * 12 * 64) return;
    int lane = tid & 63;
    int f    = (tid >> 6) % 12;
    int Gall = tid / (12 * 64);
    int kx = f >> 2, ks = f & 3;
    int g = lane >> 4;
    sv8 v;
    if (Gall < 4) v = gather_wfrag(Wg, Gall * 16 + (lane & 15), g, kx, ks);
    else          v = gather_wfrag(Wc, (Gall - 4) * 16 + (lane & 15), g, kx, ks);
    *(sv8*)&pack[(size_t)tid * 8] = v;
}

__global__ __launch_bounds__(256) void x_to_bf16(const float* __restrict__ x,
                                                 u16* __restrict__ xbf) {
    int gid = blockIdx.x * 256 + threadIdx.x;
    if (gid >= BB * TT * HW) return;
    int p  = gid & (HW - 1);
    int bt = gid >> 14;
    int t = bt % TT, b = bt / TT;
    sv8 v;
#pragma unroll
    for (int c = 0; c < 8; ++c)
        v[c] = (short)f2bf(x[(((size_t)b * CIN + c) * TT + t) * HW + p]);
    *(sv8*)&xbf[(size_t)gid * 8] = v;
}

// ---------------------------------------------------------------------------
// Persistent GRU: 512 blocks x 256 thr (4 waves), 2 blocks/CU, 16x16 tiles.
// Wave w: coPair = w>>1 (gates groups 2p,2p+1), parity = w&1 (n-tile split).
// Every LDS B-read feeds 2 MFMAs. Weights reloaded per phase from L2 (issued
// early); LDS stride 44 kills bank conflicts. Fence-free p2p neighbor sync.
// ---------------------------------------------------------------------------
__global__ __launch_bounds__(256, 2) void gru_persist(
    const u16* __restrict__ xbf, const u16* __restrict__ wpack,
    const float* __restrict__ bg, const float* __restrict__ bc,
    u16* __restrict__ hG, int* __restrict__ flags,
    float* __restrict__ out, float* __restrict__ hlast)
{
    __shared__ __align__(16) u16 smem[SMEM_U16];
    const int id = blockIdx.x;
    const int b = id & 7, tau = id >> 3;
    const int bx = tau & 7, by = tau >> 3;
    const int x0 = bx * 16, y0 = by * 16;
    const int tid = threadIdx.x, lane = tid & 63, w = tid >> 6;
    const int m = lane & 15, g = lane >> 4;

    // neighbor ids (8 dirs), -1 if outside image (8x8 tile grid)
    int nbr = -1;
    if (tid < 8) {
        const int dxs[8] = {-1, 0, 1, -1, 1, -1, 0, 1};
        const int dys[8] = {-1, -1, -1, 0, 0, 1, 1, 1};
        int nx = bx + dxs[tid], ny = by + dys[tid];
        if ((unsigned)nx < 8u && (unsigned)ny < 8u)
            nbr = ((ny * 8 + nx) * 8 + b);
    }

    // per-lane K decomposition and affine LDS offsets
    int kyv[4], ci0v[4], koff1[4], coffC[4], kstrC[4];
    bool isX[4];
#pragma unroll
    for (int ks = 0; ks < 4; ++ks) {
        int k0 = ks * 32 + g * 8;
        int ky = 0, ci0 = 0;
        if (k0 < 120) { ky = k0 / 40; ci0 = k0 - ky * 40; }
        kyv[ks] = ky; ci0v[ks] = ci0;
        koff1[ks] = ky * (T1W * S1) + ci0;                 // gates: tile1
        isX[ks]   = (ci0 == 0);                            // cand: x from tile1
        coffC[ks] = isX[ks] ? ky * (T1W * S1) : ky * (18 * S2) + (ci0 - 8);
        kstrC[ks] = isX[ks] ? S1 : S2;
    }

    const int coPair = w >> 1;          // 0: reset (co 0..31), 1: update
    const int parity = w & 1;           // n-tile split within the pair
    const int co0A = coPair * 32 + g * 4;
    const int co0B = co0A + 16;
    const int grpA = coPair * 2, grpB = grpA + 1;

    // zero tile1 h slots (h0 = 0): 400 px x 8 ull
    for (int i = tid; i < 3200; i += 256) {
        int px = i >> 3, q = i & 7;
        *(ull*)&smem[px * S1 + 8 + q * 4] = 0ull;
    }

    const u16* xbB = xbf + (size_t)b * TT * HW * 8;
    const size_t planeElems = (size_t)BB * HW * 32;

    for (int t = 0; t < TT; ++t) {
        const u16* hGr = hG + (size_t)(t & 1) * planeElems + (size_t)b * HW * 32;
        u16*       hGw = hG + (size_t)((t + 1) & 1) * planeElems + (size_t)b * HW * 32;

        // ---- gates weights (2 groups): issue early, land during wait ----
        sv8 wfA[12], wfB[12];
#pragma unroll
        for (int f = 0; f < 12; ++f) {
            wfA[f] = *(const sv8*)&wpack[(((size_t)grpA * 12 + f) * 64 + lane) * 8];
            wfB[f] = *(const sv8*)&wpack[(((size_t)grpB * 12 + f) * 64 + lane) * 8];
        }

        // ---- stage x (400 px), independent of neighbors ----
        const u16* xb = xbB + (size_t)t * HW * 8;
        for (int idx = tid; idx < 400; idx += 256) {
            int r = idx / 20, c = idx - r * 20;
            int gy = y0 + r - 2, gx = x0 + c - 2;
            sv8 v = {};
            if ((unsigned)gy < 128u && (unsigned)gx < 128u)
                v = *(const sv8*)&xb[(size_t)(gy * WW + gx) * 8];
            *(sv4*)&smem[idx * S1]     = __builtin_shufflevector(v, v, 0,1,2,3);
            *(sv4*)&smem[idx * S1 + 4] = __builtin_shufflevector(v, v, 4,5,6,7);
        }

        // ---- wait for neighbors (step t-1) ----
        if (t > 0) {
            if (tid < 8 && nbr >= 0) {
                while (__hip_atomic_load(&flags[nbr * 32], __ATOMIC_RELAXED,
                                         __HIP_MEMORY_SCOPE_AGENT) < t)
                    __builtin_amdgcn_s_sleep(8);
            }
            __syncthreads();
        }

        // ---- stage h ring (144 px x 32ch) via 8B relaxed atomics ----
        for (int idx = tid; idx < 1152; idx += 256) {
            int i = idx >> 3, q = idx & 7;
            int r, c; band_rc(i, r, c);
            int gy = y0 + r - 2, gx = x0 + c - 2;
            ull v = 0;
            if ((unsigned)gy < 128u && (unsigned)gx < 128u)
                v = __hip_atomic_load((const ull*)&hGr[(size_t)(gy * WW + gx) * 32 + q * 4],
                                      __ATOMIC_RELAXED, __HIP_MEMORY_SCOPE_AGENT);
            *(ull*)&smem[(r * T1W + c) * S1 + 8 + q * 4] = v;
        }
        __syncthreads();

        // ---- gates conv over 18x18 region (324 px = 21 n-tiles, parity split)
        f32x4 bgA = *(const f32x4*)&bg[co0A];
        f32x4 bgB = *(const f32x4*)&bg[co0B];
        for (int nt = parity; nt < 21; nt += 2) {
            int px = nt * 16 + m;
            bool val = px < 324;
            if (!val) px = 323;
            int yy = px / 18, xx = px - yy * 18;
            int pb = (yy * T1W + xx) * S1;
            f32x4 aA = {0.f,0.f,0.f,0.f}, aB = {0.f,0.f,0.f,0.f};
#pragma unroll
            for (int kx = 0; kx < 3; ++kx)
#pragma unroll
                for (int ks = 0; ks < 4; ++ks) {
                    int a = pb + kx * S1 + koff1[ks];
                    sv4 lo = *(const sv4*)&smem[a];
                    sv4 hi = *(const sv4*)&smem[a + 4];
                    sv8 bv = __builtin_shufflevector(lo, hi, 0,1,2,3,4,5,6,7);
                    aA = __builtin_amdgcn_mfma_f32_16x16x32_bf16(wfA[kx*4+ks], bv, aA, 0, 0, 0);
                    aB = __builtin_amdgcn_mfma_f32_16x16x32_bf16(wfB[kx*4+ks], bv, aB, 0, 0, 0);
                }
            if (coPair == 0) {      // reset: rh -> tile2 (both groups)
                int ctr = pb + 21 * S1 + 8;   // (yy+1, xx+1) pixel, h slots
                sv4 h4A = *(const sv4*)&smem[ctr + co0A];
                sv4 h4B = *(const sv4*)&smem[ctr + co0B];
                sv4 rhA, rhB;
#pragma unroll
                for (int r = 0; r < 4; ++r) {
                    rhA[r] = (short)f2bf(sigmoid_fast(aA[r] + bgA[r]) * bf2f((u16)h4A[r]));
                    rhB[r] = (short)f2bf(sigmoid_fast(aB[r] + bgB[r]) * bf2f((u16)h4B[r]));
                }
                if (val) {
                    *(sv4*)&smem[OFF2 + px * S2 + co0A] = rhA;
                    *(sv4*)&smem[OFF2 + px * S2 + co0B] = rhB;
                }
            } else {                // update: u -> tileU (interior only)
                sv4 uA, uB;
#pragma unroll
                for (int r = 0; r < 4; ++r) {
                    uA[r] = (short)__half_as_ushort(__float2half(sigmoid_fast(aA[r] + bgA[r])));
                    uB[r] = (short)__half_as_ushort(__float2half(sigmoid_fast(aB[r] + bgB[r])));
                }
                if (val && yy >= 1 && yy <= 16 && xx >= 1 && xx <= 16) {
                    int ub = OFFU + ((yy - 1) * 16 + (xx - 1)) * S2;
                    *(sv4*)&smem[ub + (co0A - 32)] = uA;
                    *(sv4*)&smem[ub + (co0B - 32)] = uB;
                }
            }
        }

        // ---- cand weights (both groups): issue before barrier ----
        sv8 wcA[12], wcB[12];
#pragma unroll
        for (int f = 0; f < 12; ++f) {
            wcA[f] = *(const sv8*)&wpack[(((size_t)4 * 12 + f) * 64 + lane) * 8];
            wcB[f] = *(const sv8*)&wpack[(((size_t)5 * 12 + f) * 64 + lane) * 8];
        }
        __syncthreads();

        // ---- cand conv: wave owns 4 rows, both co-groups ----
        const int j0 = w * 4;
        int rowb1[4], rowb2[4];
#pragma unroll
        for (int jr = 0; jr < 4; ++jr) {
            rowb1[jr] = ((j0 + jr + 1) * T1W + m + 1) * S1;
            rowb2[jr] = OFF2 + ((j0 + jr) * 18 + m) * S2;
        }
        f32x4 a2A[4], a2B[4];
#pragma unroll
        for (int jr = 0; jr < 4; ++jr) {
            a2A[jr] = (f32x4){0.f,0.f,0.f,0.f};
            a2B[jr] = (f32x4){0.f,0.f,0.f,0.f};
        }
#pragma unroll
        for (int kx = 0; kx < 3; ++kx)
#pragma unroll
            for (int ks = 0; ks < 4; ++ks) {
#pragma unroll
                for (int jr = 0; jr < 4; ++jr) {
                    int a = (isX[ks] ? rowb1[jr] : rowb2[jr]) + coffC[ks] + kx * kstrC[ks];
                    sv4 lo = *(const sv4*)&smem[a];
                    sv4 hi = *(const sv4*)&smem[a + 4];
                    sv8 bv = __builtin_shufflevector(lo, hi, 0,1,2,3,4,5,6,7);
                    a2A[jr] = __builtin_amdgcn_mfma_f32_16x16x32_bf16(wcA[kx*4+ks], bv, a2A[jr], 0, 0, 0);
                    a2B[jr] = __builtin_amdgcn_mfma_f32_16x16x32_bf16(wcB[kx*4+ks], bv, a2B[jr], 0, 0, 0);
                }
            }

        // ---- blend (both groups); ring stores now, out stores after flag ----
        f32x4 bcA = *(const f32x4*)&bc[g * 4];
        f32x4 bcB = *(const f32x4*)&bc[16 + g * 4];
        const int cA = g * 4, cB = 16 + g * 4;
#pragma unroll
        for (int jr = 0; jr < 4; ++jr) {
            int j = j0 + jr;
            int gy = y0 + j, gx = x0 + m;
            int ctr = ((j + 2) * T1W + m + 2) * S1 + 8;
            int ub  = OFFU + (j * 16 + m) * S2;
            sv4 h4A = *(const sv4*)&smem[ctr + cA];
            sv4 h4B = *(const sv4*)&smem[ctr + cB];
            sv4 u4A = *(const sv4*)&smem[ub + cA];
            sv4 u4B = *(const sv4*)&smem[ub + cB];
            sv4 hnA, hnB;
#pragma unroll
            for (int r = 0; r < 4; ++r) {
                float cv = tanh_fast(a2A[jr][r] + bcA[r]);
                float uu = __half2float(__ushort_as_half((u16)u4A[r]));
                float hn = (1.f - uu) * bf2f((u16)h4A[r]) + uu * cv;
                a2A[jr][r] = hn; hnA[r] = (short)f2bf(hn);
                cv = tanh_fast(a2B[jr][r] + bcB[r]);
                uu = __half2float(__ushort_as_half((u16)u4B[r]));
                hn = (1.f - uu) * bf2f((u16)h4B[r]) + uu * cv;
                a2B[jr][r] = hn; hnB[r] = (short)f2bf(hn);
            }
            *(sv4*)&smem[ctr + cA] = hnA;
            *(sv4*)&smem[ctr + cB] = hnB;
            if (j <= 1 || j >= 14 || m <= 1 || m >= 14) {
                union { sv4 s; ull u; } ca, cb; ca.s = hnA; cb.s = hnB;
                ull* base = (ull*)&hGw[(size_t)(gy * WW + gx) * 32];
                __hip_atomic_store(base + (cA >> 2), ca.u, __ATOMIC_RELAXED,
                                   __HIP_MEMORY_SCOPE_AGENT);
                __hip_atomic_store(base + (cB >> 2), cb.u, __ATOMIC_RELAXED,
                                   __HIP_MEMORY_SCOPE_AGENT);
            }
        }

        // ring stores at coherence point -> post flag (out stores not yet issued)
        asm volatile("s_waitcnt vmcnt(0)" ::: "memory");
        __syncthreads();
        if (tid == 0)
            __hip_atomic_store(&flags[id * 32], t + 1, __ATOMIC_RELAXED,
                               __HIP_MEMORY_SCOPE_AGENT);

        // ---- out (+hlast) non-temporal stores: drain during next wait ----
#pragma unroll
        for (int jr = 0; jr < 4; ++jr) {
            int j = j0 + jr;
            int gy = y0 + j, gx = x0 + m;
#pragma unroll
            for (int r = 0; r < 4; ++r) {
                __builtin_nontemporal_store(a2A[jr][r],
                    &out[(((size_t)b * HID + cA + r) * TT + t) * HW + (size_t)gy * WW + gx]);
                __builtin_nontemporal_store(a2B[jr][r],
                    &out[(((size_t)b * HID + cB + r) * TT + t) * HW + (size_t)gy * WW + gx]);
                if (t == TT - 1) {
                    __builtin_nontemporal_store(a2A[jr][r],
                        &hlast[((size_t)b * HID + cA + r) * HW + (size_t)gy * WW + gx]);
                    __builtin_nontemporal_store(a2B[jr][r],
                        &hlast[((size_t)b * HID + cB + r) * HW + (size_t)gy * WW + gx]);
                }
            }
        }
    }
}

extern "C" void kernel_launch(void* const* d_in, const int* in_sizes, int n_in,
                              void* d_out, int out_size, void* d_ws, size_t ws_size,
                              hipStream_t stream) {
    const float* x  = (const float*)d_in[0];
    const float* Wg = (const float*)d_in[1];
    const float* bg = (const float*)d_in[2];
    const float* Wc = (const float*)d_in[3];
    const float* bc = (const float*)d_in[4];

    float* out   = (float*)d_out;
    float* hlast = out + (size_t)BB * HID * TT * HW;

    const size_t PLANEB = (size_t)BB * HW * 32 * sizeof(u16);    // 8.39 MB
    const size_t PACKB  = (size_t)6 * 12 * 64 * 8 * sizeof(u16); // 73.7 KB
    const size_t FLAGB  = (size_t)NBLK * 32 * sizeof(int);       // 64 KB
    char* ws = (char*)d_ws;
    u16* hG    = (u16*)ws;                        // 2 planes
    u16* wpack = (u16*)(ws + 2 * PLANEB);
    int* flags = (int*)(ws + 2 * PLANEB + PACKB);
    u16* xbf   = (u16*)(ws + 2 * PLANEB + PACKB + FLAGB);

    pack_weights<<<(6 * 12 * 64 + 255) / 256, 256, 0, stream>>>(Wg, Wc, wpack);
    x_to_bf16<<<(BB * TT * HW) / 256, 256, 0, stream>>>(x, xbf);
    hipMemsetAsync(hG, 0, PLANEB, stream);        // plane 0 = h0 = 0
    hipMemsetAsync(flags, 0, FLAGB, stream);

    gru_persist<<<NBLK, 256, 0, stream>>>(xbf, wpack, bg, bc, hG, flags,
                                          out, hlast);
}